// Round 4
// baseline (893.125 us; speedup 1.0000x reference)
//
#include <hip/hip_runtime.h>
#include <hip/hip_bf16.h>
#include <math.h>

using bf16x8 = __attribute__((ext_vector_type(8))) __bf16;
using bf16x4 = __attribute__((ext_vector_type(4))) __bf16;
using f32x4  = __attribute__((ext_vector_type(4))) float;

constexpr int B  = 2, S = 2048, H = 2048, NH = 16, HD = 128;
constexpr int H3 = 3 * H;

// ---------------------------------------------------------------------------
// fp32 -> bf16 elementwise convert (4 elems/thread, float4 loads)
// ---------------------------------------------------------------------------
__global__ __launch_bounds__(256) void cvt_f32_bf16(
    const float* __restrict__ in, __bf16* __restrict__ out) {
  long i = ((long)blockIdx.x * 256 + threadIdx.x) * 4;
  float4 v = *(const float4*)(in + i);
  bf16x4 o;
  o[0] = (__bf16)v.x; o[1] = (__bf16)v.y; o[2] = (__bf16)v.z; o[3] = (__bf16)v.w;
  *(bf16x4*)(out + i) = o;
}

// ---------------------------------------------------------------------------
// Fused transpose + convert: W[K][N] fp32 -> WT[N][K] bf16 (32x32 LDS tile)
// ---------------------------------------------------------------------------
__global__ __launch_bounds__(256) void transpose_cvt(
    const float* __restrict__ W, __bf16* __restrict__ WT, int K, int N) {
  __shared__ float tile[32][33];
  int tx = threadIdx.x & 31, ty = threadIdx.x >> 5;
  int n0 = blockIdx.x * 32, k0 = blockIdx.y * 32;
#pragma unroll
  for (int r = 0; r < 4; ++r)
    tile[ty + r * 8][tx] = W[(long)(k0 + ty + r * 8) * N + n0 + tx];
  __syncthreads();
#pragma unroll
  for (int r = 0; r < 4; ++r)
    WT[(long)(n0 + ty + r * 8) * K + k0 + tx] = (__bf16)tile[tx][ty + r * 8];
}

// ---------------------------------------------------------------------------
// GEMM: C[M][N] = A[M][K] x BT[N][K]^T, bf16 in, fp32 acc, OutT out.
// 128x128 block tile, BK=32, 4 waves, each wave 64x64 (4x4 of 16x16 MFMA).
// Cross-validated against the naive fp32 pipeline (round 3): outputs match
// to bf16 rounding.
// ---------------------------------------------------------------------------
template <typename OutT>
__global__ __launch_bounds__(256) void gemm_bt(
    const __bf16* __restrict__ A, const __bf16* __restrict__ BT,
    OutT* __restrict__ C, int M, int N, int K) {
  constexpr int BK = 32;
  __shared__ __align__(16) __bf16 As[128 * BK];
  __shared__ __align__(16) __bf16 Bs[128 * BK];
  int tid  = threadIdx.x;
  int lane = tid & 63, w = tid >> 6;
  int quad = lane >> 4, l16 = lane & 15;
  long m0 = (long)blockIdx.y * 128, n0 = (long)blockIdx.x * 128;
  int wm = (w & 1) * 64, wn = (w >> 1) * 64;
  f32x4 acc[4][4] = {};
  const __bf16* Abase = A + m0 * K;
  const __bf16* Bbase = BT + n0 * K;
  int sr = tid >> 2;            // staging row 0..63 (and +64)
  int sc = (tid & 3) * 8;       // staging col group
  for (int kt = 0; kt < K; kt += BK) {
    *(uint4*)&As[sr * BK + sc]        = *(const uint4*)&Abase[(long)sr * K + kt + sc];
    *(uint4*)&As[(sr + 64) * BK + sc] = *(const uint4*)&Abase[(long)(sr + 64) * K + kt + sc];
    *(uint4*)&Bs[sr * BK + sc]        = *(const uint4*)&Bbase[(long)sr * K + kt + sc];
    *(uint4*)&Bs[(sr + 64) * BK + sc] = *(const uint4*)&Bbase[(long)(sr + 64) * K + kt + sc];
    __syncthreads();
    bf16x8 af[4], bfr[4];
#pragma unroll
    for (int i = 0; i < 4; ++i)
      af[i] = *(const bf16x8*)&As[(wm + i * 16 + l16) * BK + quad * 8];
#pragma unroll
    for (int j = 0; j < 4; ++j)
      bfr[j] = *(const bf16x8*)&Bs[(wn + j * 16 + l16) * BK + quad * 8];
#pragma unroll
    for (int i = 0; i < 4; ++i)
#pragma unroll
      for (int j = 0; j < 4; ++j)
        acc[i][j] = __builtin_amdgcn_mfma_f32_16x16x32_bf16(af[i], bfr[j], acc[i][j], 0, 0, 0);
    __syncthreads();
  }
  // Epilogue: C/D layout col=lane&15, row=quad*4+reg
#pragma unroll
  for (int i = 0; i < 4; ++i) {
    long rr = m0 + wm + i * 16 + quad * 4;
#pragma unroll
    for (int j = 0; j < 4; ++j) {
      long cc = n0 + wn + j * 16 + l16;
#pragma unroll
      for (int reg = 0; reg < 4; ++reg)
        C[(rr + reg) * N + cc] = (OutT)acc[i][j][reg];
    }
  }
}

// ---------------------------------------------------------------------------
// RoPE + scatter: QKV[B*S][3*H] -> Qr,Kr [B,NH,S,HD] (roped), Vt [B,NH,HD,S]
// ---------------------------------------------------------------------------
__global__ __launch_bounds__(256) void rope_scatter(
    const __bf16* __restrict__ QKV, __bf16* __restrict__ Qr,
    __bf16* __restrict__ Kr, __bf16* __restrict__ Vt) {
  int idx = blockIdx.x * 256 + threadIdx.x;
  int i  = idx & 63;
  int nh = (idx >> 6) & (NH - 1);
  int s  = (idx >> 10) & (S - 1);
  int b  = idx >> 21;
  const __bf16* p = QKV + (long)(b * S + s) * H3 + nh * HD;
  float q1 = (float)p[i],         q2 = (float)p[i + 64];
  float k1 = (float)p[H + i],     k2 = (float)p[H + i + 64];
  float v1 = (float)p[2 * H + i], v2 = (float)p[2 * H + i + 64];
  float inv_freq = expf(-(float)i * 0.14391157f);  // 10000^(-i/64)
  float fr = (float)s * inv_freq;
  float c = cosf(fr), sn = sinf(fr);
  float qa = q1 * c - q2 * sn, qb = q2 * c + q1 * sn;
  float ka = k1 * c - k2 * sn, kb = k2 * c + k1 * sn;
  long hrow = (long)(b * NH + nh) * S + s;
  Qr[hrow * HD + i]      = (__bf16)qa;
  Qr[hrow * HD + i + 64] = (__bf16)qb;
  Kr[hrow * HD + i]      = (__bf16)ka;
  Kr[hrow * HD + i + 64] = (__bf16)kb;
  long vb = (long)(b * NH + nh) * HD;
  Vt[(vb + i) * S + s]      = (__bf16)v1;
  Vt[(vb + i + 64) * S + s] = (__bf16)v2;
}

// ---------------------------------------------------------------------------
// Flash attention (causal). Block = (q-tile of 64, head, batch), 4 waves,
// wave w owns q rows [qt*64+w*16, +16). K-tiles of 64. Online softmax.
// O written to [B, S, NH, HD] (bf16, feeds the out-proj GEMM).
// ---------------------------------------------------------------------------
__global__ __launch_bounds__(256) void flash_attn(
    const __bf16* __restrict__ Q, const __bf16* __restrict__ K,
    const __bf16* __restrict__ Vt, __bf16* __restrict__ O) {
  __shared__ __align__(16) __bf16 Pl[4][16 * 64];
  int tid  = threadIdx.x;
  int lane = tid & 63, w = tid >> 6;
  int quad = lane >> 4, l16 = lane & 15;
  int qt = blockIdx.x, nh = blockIdx.y, b = blockIdx.z;
  int head = b * NH + nh;
  const __bf16* Qp = Q  + (long)head * S * HD;
  const __bf16* Kp = K  + (long)head * S * HD;
  const __bf16* Vp = Vt + (long)head * HD * S;
  int qrow = qt * 64 + w * 16;
  bf16x8 aq[4];
#pragma unroll
  for (int c = 0; c < 4; ++c)
    aq[c] = *(const bf16x8*)&Qp[(long)(qrow + l16) * HD + c * 32 + quad * 8];
  f32x4 o[8] = {};
  float m_i[4], l_i[4];
#pragma unroll
  for (int r = 0; r < 4; ++r) { m_i[r] = -1e30f; l_i[r] = 0.0f; }
  const float scale = 0.08838834764831845f;  // 1/sqrt(128)
  int ktiles = qt + 1;
  for (int t = 0; t < ktiles; ++t) {
    int kt = t * 64;
    bool last = (t == ktiles - 1);
    f32x4 sf[4];
#pragma unroll
    for (int j = 0; j < 4; ++j) {
      f32x4 acc = {};
#pragma unroll
      for (int c = 0; c < 4; ++c) {
        bf16x8 kb = *(const bf16x8*)&Kp[(long)(kt + j * 16 + l16) * HD + c * 32 + quad * 8];
        acc = __builtin_amdgcn_mfma_f32_16x16x32_bf16(aq[c], kb, acc, 0, 0, 0);
      }
      sf[j] = acc;
    }
    float alpha[4];
#pragma unroll
    for (int r = 0; r < 4; ++r) {
      int row = qrow + quad * 4 + r;
      float rowmax = -1e30f;
#pragma unroll
      for (int j = 0; j < 4; ++j) {
        float v = sf[j][r] * scale;
        if (last && (kt + j * 16 + l16) > row) v = -1e30f;  // causal mask
        sf[j][r] = v;
        rowmax = fmaxf(rowmax, v);
      }
#pragma unroll
      for (int off = 1; off < 16; off <<= 1)
        rowmax = fmaxf(rowmax, __shfl_xor(rowmax, off, 16));
      float mn = fmaxf(m_i[r], rowmax);
      float al = __expf(m_i[r] - mn);
      float ps = 0.0f;
#pragma unroll
      for (int j = 0; j < 4; ++j) {
        float pj = __expf(sf[j][r] - mn);
        sf[j][r] = pj;
        ps += pj;
      }
#pragma unroll
      for (int off = 1; off < 16; off <<= 1)
        ps += __shfl_xor(ps, off, 16);
      l_i[r] = l_i[r] * al + ps;
      m_i[r] = mn;
      alpha[r] = al;
    }
#pragma unroll
    for (int jn = 0; jn < 8; ++jn)
#pragma unroll
      for (int r = 0; r < 4; ++r)
        o[jn][r] *= alpha[r];
    // P: C-layout -> LDS -> A-layout (verified m120 pattern)
#pragma unroll
    for (int j = 0; j < 4; ++j)
#pragma unroll
      for (int r = 0; r < 4; ++r)
        Pl[w][(quad * 4 + r) * 64 + j * 16 + l16] = (__bf16)sf[j][r];
    __syncthreads();
#pragma unroll
    for (int kc = 0; kc < 2; ++kc) {
      bf16x8 pf = *(const bf16x8*)&Pl[w][l16 * 64 + kc * 32 + quad * 8];
#pragma unroll
      for (int jn = 0; jn < 8; ++jn) {
        bf16x8 vbf = *(const bf16x8*)&Vp[(long)(jn * 16 + l16) * S + kt + kc * 32 + quad * 8];
        o[jn] = __builtin_amdgcn_mfma_f32_16x16x32_bf16(pf, vbf, o[jn], 0, 0, 0);
      }
    }
    __syncthreads();
  }
#pragma unroll
  for (int r = 0; r < 4; ++r) {
    int srow = qrow + quad * 4 + r;
    float inv = 1.0f / l_i[r];
    long base = ((long)(b * S + srow) * NH + nh) * HD;
#pragma unroll
    for (int jn = 0; jn < 8; ++jn)
      O[base + jn * 16 + l16] = (__bf16)(o[jn][r] * inv);
  }
}

// ---------------------------------------------------------------------------
extern "C" void kernel_launch(void* const* d_in, const int* in_sizes, int n_in,
                              void* d_out, int out_size, void* d_ws, size_t ws_size,
                              hipStream_t stream) {
  // Identify tensors by element count; disambiguate input vs mask on device
  // is unnecessary: declared dict order is (input, mask, Wqkv, Wo), and the
  // size scan below is robust to reordering of the weights.
  int idx_wqkv = -1, idx_wo = -1, idx8[2] = {-1, -1};
  int n8 = 0;
  for (int i = 0; i < n_in; ++i) {
    if (in_sizes[i] == H * H3) idx_wqkv = i;
    else if (in_sizes[i] == H * H) idx_wo = i;
    else if (in_sizes[i] == B * S * H && n8 < 2) idx8[n8++] = i;
  }
  if (idx_wqkv < 0 || idx_wo < 0 || n8 != 2) return;
  const float* X    = (const float*)d_in[idx8[0]];  // input_tensor (dict order)
  const float* Wqkv = (const float*)d_in[idx_wqkv]; // [H, 3H] fp32
  const float* Wo   = (const float*)d_in[idx_wo];   // [H, H] fp32
  float* out = (float*)d_out;                       // [B,S,H] fp32 (!!)

  char* ws = (char*)d_ws;
  size_t off = 0;
  auto carve = [&](size_t bytes) { void* p = ws + off; off += bytes; return p; };
  __bf16* WqkvT = (__bf16*)carve((size_t)H3 * H * 2);       // [3H][H]
  __bf16* WoT   = (__bf16*)carve((size_t)H * H * 2);        // [H][H]
  __bf16* QKV   = (__bf16*)carve((size_t)B * S * H3 * 2);   // [B*S][3H]
  __bf16* Qr    = (__bf16*)carve((size_t)B * NH * S * HD * 2);
  __bf16* Kr    = (__bf16*)carve((size_t)B * NH * S * HD * 2);
  __bf16* Vt    = (__bf16*)carve((size_t)B * NH * HD * S * 2);
  __bf16* Xb    = (__bf16*)carve((size_t)B * S * H * 2);    // X bf16; reused as AO
  __bf16* AO    = Xb;  // X is dead after QKV GEMM; alias to save workspace
  if (off > ws_size) return;

  cvt_f32_bf16<<<(B * S * H) / 1024, 256, 0, stream>>>(X, Xb);
  transpose_cvt<<<dim3(H3 / 32, H / 32), 256, 0, stream>>>(Wqkv, WqkvT, H, H3);
  transpose_cvt<<<dim3(H / 32, H / 32), 256, 0, stream>>>(Wo, WoT, H, H);
  gemm_bt<__bf16><<<dim3(H3 / 128, (B * S) / 128), 256, 0, stream>>>(
      Xb, WqkvT, QKV, B * S, H3, H);
  rope_scatter<<<(B * S * NH * 64) / 256, 256, 0, stream>>>(QKV, Qr, Kr, Vt);
  flash_attn<<<dim3(S / 64, NH, B), 256, 0, stream>>>(Qr, Kr, Vt, AO);
  gemm_bt<float><<<dim3(H / 128, (B * S) / 128), 256, 0, stream>>>(
      AO, WoT, out, B * S, H, H);
}

// Round 5
// 551.986 us; speedup vs baseline: 1.6180x; 1.6180x over previous
//
#include <hip/hip_runtime.h>
#include <hip/hip_bf16.h>
#include <math.h>

using bf16x8 = __attribute__((ext_vector_type(8))) __bf16;
using bf16x4 = __attribute__((ext_vector_type(4))) __bf16;
using f32x4  = __attribute__((ext_vector_type(4))) float;

constexpr int B  = 2, S = 2048, H = 2048, NH = 16, HD = 128;
constexpr int H3 = 3 * H;

__device__ __forceinline__ void async16(const __bf16* g, __bf16* l) {
  __builtin_amdgcn_global_load_lds(
      (const __attribute__((address_space(1))) void*)g,
      (__attribute__((address_space(3))) void*)l, 16, 0, 0);
}

// ---------------------------------------------------------------------------
// fp32 -> bf16 elementwise convert (4 elems/thread, float4 loads)
// ---------------------------------------------------------------------------
__global__ __launch_bounds__(256) void cvt_f32_bf16(
    const float* __restrict__ in, __bf16* __restrict__ out) {
  long i = ((long)blockIdx.x * 256 + threadIdx.x) * 4;
  float4 v = *(const float4*)(in + i);
  bf16x4 o;
  o[0] = (__bf16)v.x; o[1] = (__bf16)v.y; o[2] = (__bf16)v.z; o[3] = (__bf16)v.w;
  *(bf16x4*)(out + i) = o;
}

// ---------------------------------------------------------------------------
// Fused transpose + convert: W[K][N] fp32 -> WT[N][K] bf16 (32x32 LDS tile)
// ---------------------------------------------------------------------------
__global__ __launch_bounds__(256) void transpose_cvt(
    const float* __restrict__ W, __bf16* __restrict__ WT, int K, int N) {
  __shared__ float tile[32][33];
  int tx = threadIdx.x & 31, ty = threadIdx.x >> 5;
  int n0 = blockIdx.x * 32, k0 = blockIdx.y * 32;
#pragma unroll
  for (int r = 0; r < 4; ++r)
    tile[ty + r * 8][tx] = W[(long)(k0 + ty + r * 8) * N + n0 + tx];
  __syncthreads();
#pragma unroll
  for (int r = 0; r < 4; ++r)
    WT[(long)(n0 + ty + r * 8) * K + k0 + tx] = (__bf16)tile[tx][ty + r * 8];
}

// ---------------------------------------------------------------------------
// GEMM: C[M][N] = A[M][K] x BT[N][K]^T, bf16 in, fp32 acc, OutT out.
// 128x128 block tile, BK=32, 4 waves, each wave 64x64 (4x4 of 16x16 MFMA).
// ---------------------------------------------------------------------------
template <typename OutT>
__global__ __launch_bounds__(256) void gemm_bt(
    const __bf16* __restrict__ A, const __bf16* __restrict__ BT,
    OutT* __restrict__ C, int M, int N, int K) {
  constexpr int BK = 32;
  __shared__ __align__(16) __bf16 As[128 * BK];
  __shared__ __align__(16) __bf16 Bs[128 * BK];
  int tid  = threadIdx.x;
  int lane = tid & 63, w = tid >> 6;
  int quad = lane >> 4, l16 = lane & 15;
  long m0 = (long)blockIdx.y * 128, n0 = (long)blockIdx.x * 128;
  int wm = (w & 1) * 64, wn = (w >> 1) * 64;
  f32x4 acc[4][4] = {};
  const __bf16* Abase = A + m0 * K;
  const __bf16* Bbase = BT + n0 * K;
  int sr = tid >> 2;            // staging row 0..63 (and +64)
  int sc = (tid & 3) * 8;       // staging col group
  for (int kt = 0; kt < K; kt += BK) {
    *(uint4*)&As[sr * BK + sc]        = *(const uint4*)&Abase[(long)sr * K + kt + sc];
    *(uint4*)&As[(sr + 64) * BK + sc] = *(const uint4*)&Abase[(long)(sr + 64) * K + kt + sc];
    *(uint4*)&Bs[sr * BK + sc]        = *(const uint4*)&Bbase[(long)sr * K + kt + sc];
    *(uint4*)&Bs[(sr + 64) * BK + sc] = *(const uint4*)&Bbase[(long)(sr + 64) * K + kt + sc];
    __syncthreads();
    bf16x8 af[4], bfr[4];
#pragma unroll
    for (int i = 0; i < 4; ++i)
      af[i] = *(const bf16x8*)&As[(wm + i * 16 + l16) * BK + quad * 8];
#pragma unroll
    for (int j = 0; j < 4; ++j)
      bfr[j] = *(const bf16x8*)&Bs[(wn + j * 16 + l16) * BK + quad * 8];
#pragma unroll
    for (int i = 0; i < 4; ++i)
#pragma unroll
      for (int j = 0; j < 4; ++j)
        acc[i][j] = __builtin_amdgcn_mfma_f32_16x16x32_bf16(af[i], bfr[j], acc[i][j], 0, 0, 0);
    __syncthreads();
  }
  // Epilogue: C/D layout col=lane&15, row=quad*4+reg
#pragma unroll
  for (int i = 0; i < 4; ++i) {
    long rr = m0 + wm + i * 16 + quad * 4;
#pragma unroll
    for (int j = 0; j < 4; ++j) {
      long cc = n0 + wn + j * 16 + l16;
#pragma unroll
      for (int reg = 0; reg < 4; ++reg)
        C[(rr + reg) * N + cc] = (OutT)acc[i][j][reg];
    }
  }
}

// ---------------------------------------------------------------------------
// RoPE + scatter: QKV[B*S][3*H] -> Qr,Kr [B,NH,S,HD], Vt [B,NH,HD,S].
// Softmax scale (1/sqrt(HD)) is folded into Q here.
// ---------------------------------------------------------------------------
__global__ __launch_bounds__(256) void rope_scatter(
    const __bf16* __restrict__ QKV, __bf16* __restrict__ Qr,
    __bf16* __restrict__ Kr, __bf16* __restrict__ Vt) {
  int idx = blockIdx.x * 256 + threadIdx.x;
  int i  = idx & 63;
  int nh = (idx >> 6) & (NH - 1);
  int s  = (idx >> 10) & (S - 1);
  int b  = idx >> 21;
  const __bf16* p = QKV + (long)(b * S + s) * H3 + nh * HD;
  float q1 = (float)p[i],         q2 = (float)p[i + 64];
  float k1 = (float)p[H + i],     k2 = (float)p[H + i + 64];
  float v1 = (float)p[2 * H + i], v2 = (float)p[2 * H + i + 64];
  float inv_freq = expf(-(float)i * 0.14391157f);  // 10000^(-i/64)
  float fr = (float)s * inv_freq;
  float c = cosf(fr), sn = sinf(fr);
  const float scale = 0.08838834764831845f;  // 1/sqrt(128), folded into Q
  float qa = (q1 * c - q2 * sn) * scale, qb = (q2 * c + q1 * sn) * scale;
  float ka = k1 * c - k2 * sn,           kb = k2 * c + k1 * sn;
  long hrow = (long)(b * NH + nh) * S + s;
  Qr[hrow * HD + i]      = (__bf16)qa;
  Qr[hrow * HD + i + 64] = (__bf16)qb;
  Kr[hrow * HD + i]      = (__bf16)ka;
  Kr[hrow * HD + i + 64] = (__bf16)kb;
  long vb = (long)(b * NH + nh) * HD;
  Vt[(vb + i) * S + s]      = (__bf16)v1;
  Vt[(vb + i + 64) * S + s] = (__bf16)v2;
}

// ---------------------------------------------------------------------------
// Flash attention (causal), m97-style LDS staging.
// Block = 256 thr (4 waves); Q-tile 64 rows (wave w -> rows w*16..+16).
// K-tile 64 double-buffered in LDS (global_load_lds w=16, prefetch t+1);
// V-tile single-buffered (latency covered by QK+softmax phase).
// All LDS tiles use 16B-granule XOR swizzle: slot = granule ^ (row & 7),
// making fragment ds_read_b128 2-way-conflict-free (free per m136).
// Heavy-first: qt = gridDim.x-1-blockIdx.x packs causal imbalance.
// ---------------------------------------------------------------------------
__global__ __launch_bounds__(256) void flash_attn(
    const __bf16* __restrict__ Q, const __bf16* __restrict__ K,
    const __bf16* __restrict__ Vt, __bf16* __restrict__ O) {
  __shared__ __align__(16) __bf16 Ks[2][64 * 128];  // 32 KB
  __shared__ __align__(16) __bf16 Vs[128 * 64];     // 16 KB
  __shared__ __align__(16) __bf16 Pl[4][16 * 64];   // 8 KB
  int tid  = threadIdx.x;
  int lane = tid & 63, w = tid >> 6;
  int quad = lane >> 4, l16 = lane & 15;
  int qt = (int)gridDim.x - 1 - (int)blockIdx.x;  // heavy blocks first
  int nh = blockIdx.y, b = blockIdx.z;
  int head = b * NH + nh;
  const __bf16* Qp = Q  + (long)head * S * HD;
  const __bf16* Kp = K  + (long)head * S * HD;
  const __bf16* Vp = Vt + (long)head * HD * S;
  int qrow = qt * 64 + w * 16;

  // K-tile staging: [64 rows][16 granules], swizzled. 4 instrs/wave.
  auto stageK = [&](int t, int buf) {
    int kt = t * 64;
#pragma unroll
    for (int it = 0; it < 4; ++it) {
      int r0  = w * 16 + it * 4;
      int row = r0 + (lane >> 4);
      int g   = (lane & 15) ^ (row & 7);
      async16(Kp + (long)(kt + row) * HD + g * 8, &Ks[buf][r0 * 128]);
    }
  };
  // V-tile staging: [128 rows][8 granules], swizzled. 4 instrs/wave.
  auto stageV = [&](int t) {
    int kt = t * 64;
#pragma unroll
    for (int it = 0; it < 4; ++it) {
      int r0  = w * 32 + it * 8;
      int row = r0 + (lane >> 3);
      int g   = (lane & 7) ^ (row & 7);
      async16(Vp + (long)row * S + kt + g * 8, &Vs[r0 * 64]);
    }
  };

  bf16x8 aq[4];
#pragma unroll
  for (int c = 0; c < 4; ++c)
    aq[c] = *(const bf16x8*)&Qp[(long)(qrow + l16) * HD + c * 32 + quad * 8];
  f32x4 o[8] = {};
  float m_i[4], l_i[4];
#pragma unroll
  for (int r = 0; r < 4; ++r) { m_i[r] = -1e30f; l_i[r] = 0.0f; }

  stageK(0, 0);
  for (int t = 0; t <= qt; ++t) {
    int kt = t * 64;
    bool last = (t == qt);
    __syncthreads();               // Ks[t&1] landed (vmcnt drained); V buf free
    if (!last) stageK(t + 1, (t + 1) & 1);  // prefetch: full phase to land
    stageV(t);                     // covered by QK + softmax below
    // ---- QK^T from LDS ----
    const __bf16* ksb = Ks[t & 1];
    f32x4 sf[4];
#pragma unroll
    for (int j = 0; j < 4; ++j) {
      f32x4 acc = {};
#pragma unroll
      for (int c = 0; c < 4; ++c) {
        int slot = (c * 4 + quad) ^ (l16 & 7);
        bf16x8 kb = *(const bf16x8*)&ksb[(j * 16 + l16) * 128 + slot * 8];
        acc = __builtin_amdgcn_mfma_f32_16x16x32_bf16(aq[c], kb, acc, 0, 0, 0);
      }
      sf[j] = acc;
    }
    // ---- online softmax (scale pre-folded into Q) ----
    float alpha[4];
#pragma unroll
    for (int r = 0; r < 4; ++r) {
      int row = qrow + quad * 4 + r;
      float rowmax = -1e30f;
#pragma unroll
      for (int j = 0; j < 4; ++j) {
        float v = sf[j][r];
        if (last && (kt + j * 16 + l16) > row) v = -1e30f;  // causal mask
        sf[j][r] = v;
        rowmax = fmaxf(rowmax, v);
      }
#pragma unroll
      for (int off = 1; off < 16; off <<= 1)
        rowmax = fmaxf(rowmax, __shfl_xor(rowmax, off, 16));
      float mn = fmaxf(m_i[r], rowmax);
      float al = __expf(m_i[r] - mn);
      float ps = 0.0f;
#pragma unroll
      for (int j = 0; j < 4; ++j) {
        float pj = __expf(sf[j][r] - mn);
        sf[j][r] = pj;
        ps += pj;
      }
#pragma unroll
      for (int off = 1; off < 16; off <<= 1)
        ps += __shfl_xor(ps, off, 16);
      l_i[r] = l_i[r] * al + ps;
      m_i[r] = mn;
      alpha[r] = al;
    }
#pragma unroll
    for (int jn = 0; jn < 8; ++jn)
#pragma unroll
      for (int r = 0; r < 4; ++r)
        o[jn][r] *= alpha[r];
    // ---- P: C-layout -> wave-private LDS (swizzled) ----
#pragma unroll
    for (int j = 0; j < 4; ++j)
#pragma unroll
      for (int r = 0; r < 4; ++r) {
        int prow = quad * 4 + r;
        int slot = (2 * j + (l16 >> 3)) ^ (prow & 7);
        Pl[w][prow * 64 + slot * 8 + (l16 & 7)] = (__bf16)sf[j][r];
      }
    __syncthreads();               // Vs landed for all waves
    // ---- PV from LDS ----
#pragma unroll
    for (int kc = 0; kc < 2; ++kc) {
      int slot = (kc * 4 + quad) ^ (l16 & 7);
      bf16x8 pf = *(const bf16x8*)&Pl[w][l16 * 64 + slot * 8];
#pragma unroll
      for (int jn = 0; jn < 8; ++jn) {
        bf16x8 vb = *(const bf16x8*)&Vs[(jn * 16 + l16) * 64 + slot * 8];
        o[jn] = __builtin_amdgcn_mfma_f32_16x16x32_bf16(pf, vb, o[jn], 0, 0, 0);
      }
    }
  }
#pragma unroll
  for (int r = 0; r < 4; ++r) {
    int srow = qrow + quad * 4 + r;
    float inv = 1.0f / l_i[r];
    long base = ((long)(b * S + srow) * NH + nh) * HD;
#pragma unroll
    for (int jn = 0; jn < 8; ++jn)
      O[base + jn * 16 + l16] = (__bf16)(o[jn][r] * inv);
  }
}

// ---------------------------------------------------------------------------
extern "C" void kernel_launch(void* const* d_in, const int* in_sizes, int n_in,
                              void* d_out, int out_size, void* d_ws, size_t ws_size,
                              hipStream_t stream) {
  int idx_wqkv = -1, idx_wo = -1, idx8[2] = {-1, -1};
  int n8 = 0;
  for (int i = 0; i < n_in; ++i) {
    if (in_sizes[i] == H * H3) idx_wqkv = i;
    else if (in_sizes[i] == H * H) idx_wo = i;
    else if (in_sizes[i] == B * S * H && n8 < 2) idx8[n8++] = i;
  }
  if (idx_wqkv < 0 || idx_wo < 0 || n8 != 2) return;
  const float* X    = (const float*)d_in[idx8[0]];  // input_tensor (dict order)
  const float* Wqkv = (const float*)d_in[idx_wqkv]; // [H, 3H] fp32
  const float* Wo   = (const float*)d_in[idx_wo];   // [H, H] fp32
  float* out = (float*)d_out;                       // [B,S,H] fp32

  char* ws = (char*)d_ws;
  size_t off = 0;
  auto carve = [&](size_t bytes) { void* p = ws + off; off += bytes; return p; };
  __bf16* WqkvT = (__bf16*)carve((size_t)H3 * H * 2);       // [3H][H]
  __bf16* WoT   = (__bf16*)carve((size_t)H * H * 2);        // [H][H]
  __bf16* QKV   = (__bf16*)carve((size_t)B * S * H3 * 2);   // [B*S][3H]
  __bf16* Qr    = (__bf16*)carve((size_t)B * NH * S * HD * 2);
  __bf16* Kr    = (__bf16*)carve((size_t)B * NH * S * HD * 2);
  __bf16* Vt    = (__bf16*)carve((size_t)B * NH * HD * S * 2);
  __bf16* Xb    = (__bf16*)carve((size_t)B * S * H * 2);    // X bf16; reused as AO
  __bf16* AO    = Xb;  // X is dead after QKV GEMM; alias to save workspace
  if (off > ws_size) return;

  cvt_f32_bf16<<<(B * S * H) / 1024, 256, 0, stream>>>(X, Xb);
  transpose_cvt<<<dim3(H3 / 32, H / 32), 256, 0, stream>>>(Wqkv, WqkvT, H, H3);
  transpose_cvt<<<dim3(H / 32, H / 32), 256, 0, stream>>>(Wo, WoT, H, H);
  gemm_bt<__bf16><<<dim3(H3 / 128, (B * S) / 128), 256, 0, stream>>>(
      Xb, WqkvT, QKV, B * S, H3, H);
  rope_scatter<<<(B * S * NH * 64) / 256, 256, 0, stream>>>(QKV, Qr, Kr, Vt);
  flash_attn<<<dim3(S / 64, NH, B), 256, 0, stream>>>(Qr, Kr, Vt, AO);
  gemm_bt<float><<<dim3(H / 128, (B * S) / 128), 256, 0, stream>>>(
      AO, WoT, out, B * S, H, H);
}

// Round 6
// 488.389 us; speedup vs baseline: 1.8287x; 1.1302x over previous
//
#include <hip/hip_runtime.h>
#include <hip/hip_bf16.h>
#include <math.h>

using bf16x8 = __attribute__((ext_vector_type(8))) __bf16;
using bf16x4 = __attribute__((ext_vector_type(4))) __bf16;
using f32x4  = __attribute__((ext_vector_type(4))) float;

constexpr int B  = 2, S = 2048, H = 2048, NH = 16, HD = 128;
constexpr int H3 = 3 * H;

__device__ __forceinline__ void async16(const __bf16* g, __bf16* l) {
  __builtin_amdgcn_global_load_lds(
      (const __attribute__((address_space(1))) void*)g,
      (__attribute__((address_space(3))) void*)l, 16, 0, 0);
}

// ---------------------------------------------------------------------------
// fp32 -> bf16 elementwise convert (4 elems/thread, float4 loads)
// ---------------------------------------------------------------------------
__global__ __launch_bounds__(256) void cvt_f32_bf16(
    const float* __restrict__ in, __bf16* __restrict__ out) {
  long i = ((long)blockIdx.x * 256 + threadIdx.x) * 4;
  float4 v = *(const float4*)(in + i);
  bf16x4 o;
  o[0] = (__bf16)v.x; o[1] = (__bf16)v.y; o[2] = (__bf16)v.z; o[3] = (__bf16)v.w;
  *(bf16x4*)(out + i) = o;
}

// ---------------------------------------------------------------------------
// Fused transpose + convert: W[K][N] fp32 -> WT[N][K] bf16 (32x32 LDS tile)
// ---------------------------------------------------------------------------
__global__ __launch_bounds__(256) void transpose_cvt(
    const float* __restrict__ W, __bf16* __restrict__ WT, int K, int N) {
  __shared__ float tile[32][33];
  int tx = threadIdx.x & 31, ty = threadIdx.x >> 5;
  int n0 = blockIdx.x * 32, k0 = blockIdx.y * 32;
#pragma unroll
  for (int r = 0; r < 4; ++r)
    tile[ty + r * 8][tx] = W[(long)(k0 + ty + r * 8) * N + n0 + tx];
  __syncthreads();
#pragma unroll
  for (int r = 0; r < 4; ++r)
    WT[(long)(n0 + ty + r * 8) * K + k0 + tx] = (__bf16)tile[tx][ty + r * 8];
}

// ---------------------------------------------------------------------------
// GEMM: C[M][N] = A[M][K] x BT[N][K]^T, bf16 in, fp32 acc, OutT out.
// 128x128 tile, BK=32, 4 waves. Staging via global_load_lds width=16
// (m97 structure): chunk c = 1 KB = 16 rows of [row][32] row-major LDS;
// lane l -> row c*16 + l/4, col (l&3)*8. Wave w stages chunks {2w, 2w+1}.
// ---------------------------------------------------------------------------
template <typename OutT>
__global__ __launch_bounds__(256) void gemm_bt(
    const __bf16* __restrict__ A, const __bf16* __restrict__ BT,
    OutT* __restrict__ C, int M, int N, int K) {
  constexpr int BK = 32;
  __shared__ __align__(16) __bf16 As[128 * BK];
  __shared__ __align__(16) __bf16 Bs[128 * BK];
  int tid  = threadIdx.x;
  int lane = tid & 63, w = tid >> 6;
  int quad = lane >> 4, l16 = lane & 15;
  long m0 = (long)blockIdx.y * 128, n0 = (long)blockIdx.x * 128;
  int wm = (w & 1) * 64, wn = (w >> 1) * 64;
  f32x4 acc[4][4] = {};
  const __bf16* Abase = A + m0 * K;
  const __bf16* Bbase = BT + n0 * K;
  int srow = (lane >> 2);        // 0..15 within chunk
  int scol = (lane & 3) * 8;
  for (int kt = 0; kt < K; kt += BK) {
#pragma unroll
    for (int i = 0; i < 2; ++i) {
      int c = w * 2 + i;         // chunk 0..7
      int row = c * 16 + srow;
      async16(&Abase[(long)row * K + kt + scol], &As[c * 512]);
      async16(&Bbase[(long)row * K + kt + scol], &Bs[c * 512]);
    }
    __syncthreads();             // drains vmcnt: staged data visible
    bf16x8 af[4], bfr[4];
#pragma unroll
    for (int i = 0; i < 4; ++i)
      af[i] = *(const bf16x8*)&As[(wm + i * 16 + l16) * BK + quad * 8];
#pragma unroll
    for (int j = 0; j < 4; ++j)
      bfr[j] = *(const bf16x8*)&Bs[(wn + j * 16 + l16) * BK + quad * 8];
#pragma unroll
    for (int i = 0; i < 4; ++i)
#pragma unroll
      for (int j = 0; j < 4; ++j)
        acc[i][j] = __builtin_amdgcn_mfma_f32_16x16x32_bf16(af[i], bfr[j], acc[i][j], 0, 0, 0);
    __syncthreads();
  }
  // Epilogue: C/D layout col=lane&15, row=quad*4+reg
#pragma unroll
  for (int i = 0; i < 4; ++i) {
    long rr = m0 + wm + i * 16 + quad * 4;
#pragma unroll
    for (int j = 0; j < 4; ++j) {
      long cc = n0 + wn + j * 16 + l16;
#pragma unroll
      for (int reg = 0; reg < 4; ++reg)
        C[(rr + reg) * N + cc] = (OutT)acc[i][j][reg];
    }
  }
}

// ---------------------------------------------------------------------------
// RoPE + scatter: QKV[B*S][3*H] -> Qr,Kr [B,NH,S,HD], Vt [B,NH,HD,S].
// Softmax scale (1/sqrt(HD)) folded into Q.
// ---------------------------------------------------------------------------
__global__ __launch_bounds__(256) void rope_scatter(
    const __bf16* __restrict__ QKV, __bf16* __restrict__ Qr,
    __bf16* __restrict__ Kr, __bf16* __restrict__ Vt) {
  int idx = blockIdx.x * 256 + threadIdx.x;
  int i  = idx & 63;
  int nh = (idx >> 6) & (NH - 1);
  int s  = (idx >> 10) & (S - 1);
  int b  = idx >> 21;
  const __bf16* p = QKV + (long)(b * S + s) * H3 + nh * HD;
  float q1 = (float)p[i],         q2 = (float)p[i + 64];
  float k1 = (float)p[H + i],     k2 = (float)p[H + i + 64];
  float v1 = (float)p[2 * H + i], v2 = (float)p[2 * H + i + 64];
  float inv_freq = expf(-(float)i * 0.14391157f);  // 10000^(-i/64)
  float fr = (float)s * inv_freq;
  float c = cosf(fr), sn = sinf(fr);
  const float scale = 0.08838834764831845f;  // 1/sqrt(128), folded into Q
  float qa = (q1 * c - q2 * sn) * scale, qb = (q2 * c + q1 * sn) * scale;
  float ka = k1 * c - k2 * sn,           kb = k2 * c + k1 * sn;
  long hrow = (long)(b * NH + nh) * S + s;
  Qr[hrow * HD + i]      = (__bf16)qa;
  Qr[hrow * HD + i + 64] = (__bf16)qb;
  Kr[hrow * HD + i]      = (__bf16)ka;
  Kr[hrow * HD + i + 64] = (__bf16)kb;
  long vb = (long)(b * NH + nh) * HD;
  Vt[(vb + i) * S + s]      = (__bf16)v1;
  Vt[(vb + i + 64) * S + s] = (__bf16)v2;
}

// ---------------------------------------------------------------------------
// Flash attention (causal), complementary-pair Q-tiles.
// Block bx handles Q-tiles qtA=bx (0..15) and qtB=31-bx (31..16): every block
// does exactly (qtA+1)+(qtB+1) = 33 tile-computations -> perfectly balanced,
// grid 512 = exactly co-resident (2 blocks/CU x 256 CU).
// K-tile 64 double-buffered (global_load_lds w16, prefetch t+1); V-tile
// single-buffered. K/V fragments read from LDS once, fed to BOTH Q-sets.
// 16B-granule XOR swizzle on all LDS tiles.
// ---------------------------------------------------------------------------
__global__ __launch_bounds__(256, 2) void flash_attn(
    const __bf16* __restrict__ Q, const __bf16* __restrict__ K,
    const __bf16* __restrict__ Vt, __bf16* __restrict__ O) {
  __shared__ __align__(16) __bf16 Ks[2][64 * 128];   // 32 KB
  __shared__ __align__(16) __bf16 Vs[128 * 64];      // 16 KB
  __shared__ __align__(16) __bf16 Pl[4][2][16 * 64]; // 16 KB
  int tid  = threadIdx.x;
  int lane = tid & 63, w = tid >> 6;
  int quad = lane >> 4, l16 = lane & 15;
  int qtA = blockIdx.x;                      // 0..15
  int qtB = 2 * (int)gridDim.x - 1 - qtA;    // 31..16
  int nh = blockIdx.y, b = blockIdx.z;
  int head = b * NH + nh;
  const __bf16* Qp = Q  + (long)head * S * HD;
  const __bf16* Kp = K  + (long)head * S * HD;
  const __bf16* Vp = Vt + (long)head * HD * S;
  int qrow[2] = { qtA * 64 + w * 16, qtB * 64 + w * 16 };

  auto stageK = [&](int t, int buf) {
    int kt = t * 64;
#pragma unroll
    for (int it = 0; it < 4; ++it) {
      int r0  = w * 16 + it * 4;
      int row = r0 + (lane >> 4);
      int g   = (lane & 15) ^ (row & 7);
      async16(Kp + (long)(kt + row) * HD + g * 8, &Ks[buf][r0 * 128]);
    }
  };
  auto stageV = [&](int t) {
    int kt = t * 64;
#pragma unroll
    for (int it = 0; it < 4; ++it) {
      int r0  = w * 32 + it * 8;
      int row = r0 + (lane >> 3);
      int g   = (lane & 7) ^ (row & 7);
      async16(Vp + (long)row * S + kt + g * 8, &Vs[r0 * 64]);
    }
  };

  bf16x8 aq[2][4];
#pragma unroll
  for (int s = 0; s < 2; ++s)
#pragma unroll
    for (int c = 0; c < 4; ++c)
      aq[s][c] = *(const bf16x8*)&Qp[(long)(qrow[s] + l16) * HD + c * 32 + quad * 8];
  f32x4 o[2][8] = {};
  float m_i[2][4], l_i[2][4];
#pragma unroll
  for (int s = 0; s < 2; ++s)
#pragma unroll
    for (int r = 0; r < 4; ++r) { m_i[s][r] = -1e30f; l_i[s][r] = 0.0f; }

  stageK(0, 0);
  for (int t = 0; t <= qtB; ++t) {
    int kt = t * 64;
    bool aAct = (t <= qtA);
    __syncthreads();                       // Ks[t&1] landed; Vs free
    if (t < qtB) stageK(t + 1, (t + 1) & 1);
    stageV(t);
    const __bf16* ksb = Ks[t & 1];
    // ---- QK^T, K-frags read once for both sets ----
    f32x4 sf[2][4] = {};
#pragma unroll
    for (int j = 0; j < 4; ++j) {
#pragma unroll
      for (int c = 0; c < 4; ++c) {
        int slot = (c * 4 + quad) ^ (l16 & 7);
        bf16x8 kb = *(const bf16x8*)&ksb[(j * 16 + l16) * 128 + slot * 8];
        sf[1][j] = __builtin_amdgcn_mfma_f32_16x16x32_bf16(aq[1][c], kb, sf[1][j], 0, 0, 0);
        if (aAct)
          sf[0][j] = __builtin_amdgcn_mfma_f32_16x16x32_bf16(aq[0][c], kb, sf[0][j], 0, 0, 0);
      }
    }
    // ---- online softmax + P write (per set) ----
    auto smax = [&](int s, bool lastT) {
      float alpha[4];
#pragma unroll
      for (int r = 0; r < 4; ++r) {
        int row = qrow[s] + quad * 4 + r;
        float rowmax = -1e30f;
#pragma unroll
        for (int j = 0; j < 4; ++j) {
          float v = sf[s][j][r];
          if (lastT && (kt + j * 16 + l16) > row) v = -1e30f;  // causal mask
          sf[s][j][r] = v;
          rowmax = fmaxf(rowmax, v);
        }
#pragma unroll
        for (int off = 1; off < 16; off <<= 1)
          rowmax = fmaxf(rowmax, __shfl_xor(rowmax, off, 16));
        float mn = fmaxf(m_i[s][r], rowmax);
        float al = __expf(m_i[s][r] - mn);
        float ps = 0.0f;
#pragma unroll
        for (int j = 0; j < 4; ++j) {
          float pj = __expf(sf[s][j][r] - mn);
          sf[s][j][r] = pj;
          ps += pj;
        }
#pragma unroll
        for (int off = 1; off < 16; off <<= 1)
          ps += __shfl_xor(ps, off, 16);
        l_i[s][r] = l_i[s][r] * al + ps;
        m_i[s][r] = mn;
        alpha[r] = al;
      }
#pragma unroll
      for (int jn = 0; jn < 8; ++jn)
#pragma unroll
        for (int r = 0; r < 4; ++r)
          o[s][jn][r] *= alpha[r];
#pragma unroll
      for (int j = 0; j < 4; ++j)
#pragma unroll
        for (int r = 0; r < 4; ++r) {
          int prow = quad * 4 + r;
          int slot = (2 * j + (l16 >> 3)) ^ (prow & 7);
          Pl[w][s][prow * 64 + slot * 8 + (l16 & 7)] = (__bf16)sf[s][j][r];
        }
    };
    smax(1, t == qtB);
    if (aAct) smax(0, t == qtA);
    __syncthreads();                       // Vs landed for all waves
    // ---- PV, V-frags read once for both sets ----
#pragma unroll
    for (int kc = 0; kc < 2; ++kc) {
      int slot = (kc * 4 + quad) ^ (l16 & 7);
      bf16x8 pfB = *(const bf16x8*)&Pl[w][1][l16 * 64 + slot * 8];
      bf16x8 pfA;
      if (aAct) pfA = *(const bf16x8*)&Pl[w][0][l16 * 64 + slot * 8];
#pragma unroll
      for (int jn = 0; jn < 8; ++jn) {
        bf16x8 vb = *(const bf16x8*)&Vs[(jn * 16 + l16) * 64 + slot * 8];
        o[1][jn] = __builtin_amdgcn_mfma_f32_16x16x32_bf16(pfB, vb, o[1][jn], 0, 0, 0);
        if (aAct)
          o[0][jn] = __builtin_amdgcn_mfma_f32_16x16x32_bf16(pfA, vb, o[0][jn], 0, 0, 0);
      }
    }
  }
#pragma unroll
  for (int s = 0; s < 2; ++s)
#pragma unroll
    for (int r = 0; r < 4; ++r) {
      int srow = qrow[s] + quad * 4 + r;
      float inv = 1.0f / l_i[s][r];
      long base = ((long)(b * S + srow) * NH + nh) * HD;
#pragma unroll
      for (int jn = 0; jn < 8; ++jn)
        O[base + jn * 16 + l16] = (__bf16)(o[s][jn][r] * inv);
    }
}

// ---------------------------------------------------------------------------
extern "C" void kernel_launch(void* const* d_in, const int* in_sizes, int n_in,
                              void* d_out, int out_size, void* d_ws, size_t ws_size,
                              hipStream_t stream) {
  int idx_wqkv = -1, idx_wo = -1, idx8[2] = {-1, -1};
  int n8 = 0;
  for (int i = 0; i < n_in; ++i) {
    if (in_sizes[i] == H * H3) idx_wqkv = i;
    else if (in_sizes[i] == H * H) idx_wo = i;
    else if (in_sizes[i] == B * S * H && n8 < 2) idx8[n8++] = i;
  }
  if (idx_wqkv < 0 || idx_wo < 0 || n8 != 2) return;
  const float* X    = (const float*)d_in[idx8[0]];  // input_tensor (dict order)
  const float* Wqkv = (const float*)d_in[idx_wqkv]; // [H, 3H] fp32
  const float* Wo   = (const float*)d_in[idx_wo];   // [H, H] fp32
  float* out = (float*)d_out;                       // [B,S,H] fp32

  char* ws = (char*)d_ws;
  size_t off = 0;
  auto carve = [&](size_t bytes) { void* p = ws + off; off += bytes; return p; };
  __bf16* WqkvT = (__bf16*)carve((size_t)H3 * H * 2);       // [3H][H]
  __bf16* WoT   = (__bf16*)carve((size_t)H * H * 2);        // [H][H]
  __bf16* QKV   = (__bf16*)carve((size_t)B * S * H3 * 2);   // [B*S][3H]
  __bf16* Qr    = (__bf16*)carve((size_t)B * NH * S * HD * 2);
  __bf16* Kr    = (__bf16*)carve((size_t)B * NH * S * HD * 2);
  __bf16* Vt    = (__bf16*)carve((size_t)B * NH * HD * S * 2);
  __bf16* Xb    = (__bf16*)carve((size_t)B * S * H * 2);    // X bf16; reused as AO
  __bf16* AO    = Xb;  // X is dead after QKV GEMM; alias to save workspace
  if (off > ws_size) return;

  cvt_f32_bf16<<<(B * S * H) / 1024, 256, 0, stream>>>(X, Xb);
  transpose_cvt<<<dim3(H3 / 32, H / 32), 256, 0, stream>>>(Wqkv, WqkvT, H, H3);
  transpose_cvt<<<dim3(H / 32, H / 32), 256, 0, stream>>>(Wo, WoT, H, H);
  gemm_bt<__bf16><<<dim3(H3 / 128, (B * S) / 128), 256, 0, stream>>>(
      Xb, WqkvT, QKV, B * S, H3, H);
  rope_scatter<<<(B * S * NH * 64) / 256, 256, 0, stream>>>(QKV, Qr, Kr, Vt);
  flash_attn<<<dim3(S / 128, NH, B), 256, 0, stream>>>(Qr, Kr, Vt, AO);
  gemm_bt<float><<<dim3(H / 128, (B * S) / 128), 256, 0, stream>>>(
      AO, WoT, out, B * S, H, H);
}

// Round 7
// 462.070 us; speedup vs baseline: 1.9329x; 1.0570x over previous
//
#include <hip/hip_runtime.h>
#include <hip/hip_bf16.h>
#include <math.h>

using bf16x8 = __attribute__((ext_vector_type(8))) __bf16;
using bf16x4 = __attribute__((ext_vector_type(4))) __bf16;
using f32x4  = __attribute__((ext_vector_type(4))) float;

constexpr int B  = 2, S = 2048, H = 2048, NH = 16, HD = 128;
constexpr int H3 = 3 * H;

__device__ __forceinline__ void async16(const __bf16* g, __bf16* l) {
  __builtin_amdgcn_global_load_lds(
      (const __attribute__((address_space(1))) void*)g,
      (__attribute__((address_space(3))) void*)l, 16, 0, 0);
}

// ---------------------------------------------------------------------------
// fp32 -> bf16 elementwise convert (4 elems/thread, float4 loads)
// ---------------------------------------------------------------------------
__global__ __launch_bounds__(256) void cvt_f32_bf16(
    const float* __restrict__ in, __bf16* __restrict__ out) {
  long i = ((long)blockIdx.x * 256 + threadIdx.x) * 4;
  float4 v = *(const float4*)(in + i);
  bf16x4 o;
  o[0] = (__bf16)v.x; o[1] = (__bf16)v.y; o[2] = (__bf16)v.z; o[3] = (__bf16)v.w;
  *(bf16x4*)(out + i) = o;
}

// ---------------------------------------------------------------------------
// Fused transpose + convert: W[K][N] fp32 -> WT[N][K] bf16 (32x32 LDS tile)
// ---------------------------------------------------------------------------
__global__ __launch_bounds__(256) void transpose_cvt(
    const float* __restrict__ W, __bf16* __restrict__ WT, int K, int N) {
  __shared__ float tile[32][33];
  int tx = threadIdx.x & 31, ty = threadIdx.x >> 5;
  int n0 = blockIdx.x * 32, k0 = blockIdx.y * 32;
#pragma unroll
  for (int r = 0; r < 4; ++r)
    tile[ty + r * 8][tx] = W[(long)(k0 + ty + r * 8) * N + n0 + tx];
  __syncthreads();
#pragma unroll
  for (int r = 0; r < 4; ++r)
    WT[(long)(n0 + ty + r * 8) * K + k0 + tx] = (__bf16)tile[tx][ty + r * 8];
}

// ---------------------------------------------------------------------------
// GEMM: C[M][N] = A[M][K] x BT[N][K]^T, bf16 in, fp32 acc, OutT out.
// 128x128 tile, BK=64, 4 waves, wave = 64x64 (4x4 of 16x16x32 MFMA, 2 k-steps).
// LDS [128 rows][8 granules of 16B], granule-XOR swizzle slot = g ^ (row&7):
//   - store: global_load_lds fixes lane l's LDS slot to l&7 at row c*8+(l>>3),
//     so lane fetches global granule (l&7) ^ (l>>3)  (row&7 == l>>3).
//   - read: fragment row r has r&7 == l16&7, so slot = (kk*4+quad) ^ (l16&7);
//     lanes 0..7 sweep all 8 slots, 8..15 repeat -> 2-way conflict = free (m136).
// 32 MFMA per barrier (2x the BK=32 version).
// ---------------------------------------------------------------------------
template <typename OutT>
__global__ __launch_bounds__(256) void gemm_bt(
    const __bf16* __restrict__ A, const __bf16* __restrict__ BT,
    OutT* __restrict__ C, int M, int N, int K) {
  constexpr int BK = 64;
  __shared__ __align__(16) __bf16 As[128 * BK];
  __shared__ __align__(16) __bf16 Bs[128 * BK];
  int tid  = threadIdx.x;
  int lane = tid & 63, w = tid >> 6;
  int quad = lane >> 4, l16 = lane & 15;
  long m0 = (long)blockIdx.y * 128, n0 = (long)blockIdx.x * 128;
  int wm = (w & 1) * 64, wn = (w >> 1) * 64;
  f32x4 acc[4][4] = {};
  const __bf16* Abase = A + m0 * K;
  const __bf16* Bbase = BT + n0 * K;
  int srow8 = lane >> 3;               // 0..7 (row within chunk)
  int sgran = (lane & 7) ^ srow8;      // global granule this lane fetches
  for (int kt = 0; kt < K; kt += BK) {
#pragma unroll
    for (int it = 0; it < 4; ++it) {
      int c   = w * 4 + it;            // chunk 0..15 (8 rows, 1 KB)
      int row = c * 8 + srow8;
      async16(&Abase[(long)row * K + kt + sgran * 8], &As[c * 512]);
      async16(&Bbase[(long)row * K + kt + sgran * 8], &Bs[c * 512]);
    }
    __syncthreads();                   // drains vmcnt: staged data visible
#pragma unroll
    for (int kk = 0; kk < 2; ++kk) {
      bf16x8 af[4], bfr[4];
#pragma unroll
      for (int i = 0; i < 4; ++i) {
        int slot = (kk * 4 + quad) ^ (l16 & 7);
        af[i] = *(const bf16x8*)&As[(wm + i * 16 + l16) * BK + slot * 8];
      }
#pragma unroll
      for (int j = 0; j < 4; ++j) {
        int slot = (kk * 4 + quad) ^ (l16 & 7);
        bfr[j] = *(const bf16x8*)&Bs[(wn + j * 16 + l16) * BK + slot * 8];
      }
#pragma unroll
      for (int i = 0; i < 4; ++i)
#pragma unroll
        for (int j = 0; j < 4; ++j)
          acc[i][j] = __builtin_amdgcn_mfma_f32_16x16x32_bf16(af[i], bfr[j], acc[i][j], 0, 0, 0);
    }
    __syncthreads();
  }
  // Epilogue: C/D layout col=lane&15, row=quad*4+reg
#pragma unroll
  for (int i = 0; i < 4; ++i) {
    long rr = m0 + wm + i * 16 + quad * 4;
#pragma unroll
    for (int j = 0; j < 4; ++j) {
      long cc = n0 + wn + j * 16 + l16;
#pragma unroll
      for (int reg = 0; reg < 4; ++reg)
        C[(rr + reg) * N + cc] = (OutT)acc[i][j][reg];
    }
  }
}

// ---------------------------------------------------------------------------
// RoPE + scatter: QKV[B*S][3*H] -> Qr,Kr [B,NH,S,HD], Vt [B,NH,HD,S].
// Softmax scale (1/sqrt(HD)) folded into Q.
// ---------------------------------------------------------------------------
__global__ __launch_bounds__(256) void rope_scatter(
    const __bf16* __restrict__ QKV, __bf16* __restrict__ Qr,
    __bf16* __restrict__ Kr, __bf16* __restrict__ Vt) {
  int idx = blockIdx.x * 256 + threadIdx.x;
  int i  = idx & 63;
  int nh = (idx >> 6) & (NH - 1);
  int s  = (idx >> 10) & (S - 1);
  int b  = idx >> 21;
  const __bf16* p = QKV + (long)(b * S + s) * H3 + nh * HD;
  float q1 = (float)p[i],         q2 = (float)p[i + 64];
  float k1 = (float)p[H + i],     k2 = (float)p[H + i + 64];
  float v1 = (float)p[2 * H + i], v2 = (float)p[2 * H + i + 64];
  float inv_freq = expf(-(float)i * 0.14391157f);  // 10000^(-i/64)
  float fr = (float)s * inv_freq;
  float c = cosf(fr), sn = sinf(fr);
  const float scale = 0.08838834764831845f;  // 1/sqrt(128), folded into Q
  float qa = (q1 * c - q2 * sn) * scale, qb = (q2 * c + q1 * sn) * scale;
  float ka = k1 * c - k2 * sn,           kb = k2 * c + k1 * sn;
  long hrow = (long)(b * NH + nh) * S + s;
  Qr[hrow * HD + i]      = (__bf16)qa;
  Qr[hrow * HD + i + 64] = (__bf16)qb;
  Kr[hrow * HD + i]      = (__bf16)ka;
  Kr[hrow * HD + i + 64] = (__bf16)kb;
  long vb = (long)(b * NH + nh) * HD;
  Vt[(vb + i) * S + s]      = (__bf16)v1;
  Vt[(vb + i + 64) * S + s] = (__bf16)v2;
}

// ---------------------------------------------------------------------------
// Flash attention (causal), complementary-pair Q-tiles.
// Block bx handles Q-tiles qtA=bx (0..15) and qtB=31-bx (31..16): every block
// does exactly 33 tile-computations -> perfectly balanced, grid 512 = exactly
// co-resident (2 blocks/CU x 256 CU). K-tile double-buffered via
// global_load_lds; V-tile single-buffered; K/V LDS fragments feed BOTH Q-sets.
// 16B-granule XOR swizzle on all LDS tiles.
// ---------------------------------------------------------------------------
__global__ __launch_bounds__(256, 2) void flash_attn(
    const __bf16* __restrict__ Q, const __bf16* __restrict__ K,
    const __bf16* __restrict__ Vt, __bf16* __restrict__ O) {
  __shared__ __align__(16) __bf16 Ks[2][64 * 128];   // 32 KB
  __shared__ __align__(16) __bf16 Vs[128 * 64];      // 16 KB
  __shared__ __align__(16) __bf16 Pl[4][2][16 * 64]; // 16 KB
  int tid  = threadIdx.x;
  int lane = tid & 63, w = tid >> 6;
  int quad = lane >> 4, l16 = lane & 15;
  int qtA = blockIdx.x;                      // 0..15
  int qtB = 2 * (int)gridDim.x - 1 - qtA;    // 31..16
  int nh = blockIdx.y, b = blockIdx.z;
  int head = b * NH + nh;
  const __bf16* Qp = Q  + (long)head * S * HD;
  const __bf16* Kp = K  + (long)head * S * HD;
  const __bf16* Vp = Vt + (long)head * HD * S;
  int qrow[2] = { qtA * 64 + w * 16, qtB * 64 + w * 16 };

  auto stageK = [&](int t, int buf) {
    int kt = t * 64;
#pragma unroll
    for (int it = 0; it < 4; ++it) {
      int r0  = w * 16 + it * 4;
      int row = r0 + (lane >> 4);
      int g   = (lane & 15) ^ (row & 7);
      async16(Kp + (long)(kt + row) * HD + g * 8, &Ks[buf][r0 * 128]);
    }
  };
  auto stageV = [&](int t) {
    int kt = t * 64;
#pragma unroll
    for (int it = 0; it < 4; ++it) {
      int r0  = w * 32 + it * 8;
      int row = r0 + (lane >> 3);
      int g   = (lane & 7) ^ (row & 7);
      async16(Vp + (long)row * S + kt + g * 8, &Vs[r0 * 64]);
    }
  };

  bf16x8 aq[2][4];
#pragma unroll
  for (int s = 0; s < 2; ++s)
#pragma unroll
    for (int c = 0; c < 4; ++c)
      aq[s][c] = *(const bf16x8*)&Qp[(long)(qrow[s] + l16) * HD + c * 32 + quad * 8];
  f32x4 o[2][8] = {};
  float m_i[2][4], l_i[2][4];
#pragma unroll
  for (int s = 0; s < 2; ++s)
#pragma unroll
    for (int r = 0; r < 4; ++r) { m_i[s][r] = -1e30f; l_i[s][r] = 0.0f; }

  stageK(0, 0);
  for (int t = 0; t <= qtB; ++t) {
    int kt = t * 64;
    bool aAct = (t <= qtA);
    __syncthreads();                       // Ks[t&1] landed; Vs free
    if (t < qtB) stageK(t + 1, (t + 1) & 1);
    stageV(t);
    const __bf16* ksb = Ks[t & 1];
    // ---- QK^T, K-frags read once for both sets ----
    f32x4 sf[2][4] = {};
#pragma unroll
    for (int j = 0; j < 4; ++j) {
#pragma unroll
      for (int c = 0; c < 4; ++c) {
        int slot = (c * 4 + quad) ^ (l16 & 7);
        bf16x8 kb = *(const bf16x8*)&ksb[(j * 16 + l16) * 128 + slot * 8];
        sf[1][j] = __builtin_amdgcn_mfma_f32_16x16x32_bf16(aq[1][c], kb, sf[1][j], 0, 0, 0);
        if (aAct)
          sf[0][j] = __builtin_amdgcn_mfma_f32_16x16x32_bf16(aq[0][c], kb, sf[0][j], 0, 0, 0);
      }
    }
    // ---- online softmax + P write (per set) ----
    auto smax = [&](int s, bool lastT) {
      float alpha[4];
#pragma unroll
      for (int r = 0; r < 4; ++r) {
        int row = qrow[s] + quad * 4 + r;
        float rowmax = -1e30f;
#pragma unroll
        for (int j = 0; j < 4; ++j) {
          float v = sf[s][j][r];
          if (lastT && (kt + j * 16 + l16) > row) v = -1e30f;  // causal mask
          sf[s][j][r] = v;
          rowmax = fmaxf(rowmax, v);
        }
#pragma unroll
        for (int off = 1; off < 16; off <<= 1)
          rowmax = fmaxf(rowmax, __shfl_xor(rowmax, off, 16));
        float mn = fmaxf(m_i[s][r], rowmax);
        float al = __expf(m_i[s][r] - mn);
        float ps = 0.0f;
#pragma unroll
        for (int j = 0; j < 4; ++j) {
          float pj = __expf(sf[s][j][r] - mn);
          sf[s][j][r] = pj;
          ps += pj;
        }
#pragma unroll
        for (int off = 1; off < 16; off <<= 1)
          ps += __shfl_xor(ps, off, 16);
        l_i[s][r] = l_i[s][r] * al + ps;
        m_i[s][r] = mn;
        alpha[r] = al;
      }
#pragma unroll
      for (int jn = 0; jn < 8; ++jn)
#pragma unroll
        for (int r = 0; r < 4; ++r)
          o[s][jn][r] *= alpha[r];
#pragma unroll
      for (int j = 0; j < 4; ++j)
#pragma unroll
        for (int r = 0; r < 4; ++r) {
          int prow = quad * 4 + r;
          int slot = (2 * j + (l16 >> 3)) ^ (prow & 7);
          Pl[w][s][prow * 64 + slot * 8 + (l16 & 7)] = (__bf16)sf[s][j][r];
        }
    };
    smax(1, t == qtB);
    if (aAct) smax(0, t == qtA);
    __syncthreads();                       // Vs landed for all waves
    // ---- PV, V-frags read once for both sets ----
#pragma unroll
    for (int kc = 0; kc < 2; ++kc) {
      int slot = (kc * 4 + quad) ^ (l16 & 7);
      bf16x8 pfB = *(const bf16x8*)&Pl[w][1][l16 * 64 + slot * 8];
      bf16x8 pfA;
      if (aAct) pfA = *(const bf16x8*)&Pl[w][0][l16 * 64 + slot * 8];
#pragma unroll
      for (int jn = 0; jn < 8; ++jn) {
        bf16x8 vb = *(const bf16x8*)&Vs[(jn * 16 + l16) * 64 + slot * 8];
        o[1][jn] = __builtin_amdgcn_mfma_f32_16x16x32_bf16(pfB, vb, o[1][jn], 0, 0, 0);
        if (aAct)
          o[0][jn] = __builtin_amdgcn_mfma_f32_16x16x32_bf16(pfA, vb, o[0][jn], 0, 0, 0);
      }
    }
  }
#pragma unroll
  for (int s = 0; s < 2; ++s)
#pragma unroll
    for (int r = 0; r < 4; ++r) {
      int srow = qrow[s] + quad * 4 + r;
      float inv = 1.0f / l_i[s][r];
      long base = ((long)(b * S + srow) * NH + nh) * HD;
#pragma unroll
      for (int jn = 0; jn < 8; ++jn)
        O[base + jn * 16 + l16] = (__bf16)(o[s][jn][r] * inv);
    }
}

// ---------------------------------------------------------------------------
extern "C" void kernel_launch(void* const* d_in, const int* in_sizes, int n_in,
                              void* d_out, int out_size, void* d_ws, size_t ws_size,
                              hipStream_t stream) {
  int idx_wqkv = -1, idx_wo = -1, idx8[2] = {-1, -1};
  int n8 = 0;
  for (int i = 0; i < n_in; ++i) {
    if (in_sizes[i] == H * H3) idx_wqkv = i;
    else if (in_sizes[i] == H * H) idx_wo = i;
    else if (in_sizes[i] == B * S * H && n8 < 2) idx8[n8++] = i;
  }
  if (idx_wqkv < 0 || idx_wo < 0 || n8 != 2) return;
  const float* X    = (const float*)d_in[idx8[0]];  // input_tensor (dict order)
  const float* Wqkv = (const float*)d_in[idx_wqkv]; // [H, 3H] fp32
  const float* Wo   = (const float*)d_in[idx_wo];   // [H, H] fp32
  float* out = (float*)d_out;                       // [B,S,H] fp32

  char* ws = (char*)d_ws;
  size_t off = 0;
  auto carve = [&](size_t bytes) { void* p = ws + off; off += bytes; return p; };
  __bf16* WqkvT = (__bf16*)carve((size_t)H3 * H * 2);       // [3H][H]
  __bf16* WoT   = (__bf16*)carve((size_t)H * H * 2);        // [H][H]
  __bf16* QKV   = (__bf16*)carve((size_t)B * S * H3 * 2);   // [B*S][3H]
  __bf16* Qr    = (__bf16*)carve((size_t)B * NH * S * HD * 2);
  __bf16* Kr    = (__bf16*)carve((size_t)B * NH * S * HD * 2);
  __bf16* Vt    = (__bf16*)carve((size_t)B * NH * HD * S * 2);
  __bf16* Xb    = (__bf16*)carve((size_t)B * S * H * 2);    // X bf16; reused as AO
  __bf16* AO    = Xb;  // X is dead after QKV GEMM; alias to save workspace
  if (off > ws_size) return;

  cvt_f32_bf16<<<(B * S * H) / 1024, 256, 0, stream>>>(X, Xb);
  transpose_cvt<<<dim3(H3 / 32, H / 32), 256, 0, stream>>>(Wqkv, WqkvT, H, H3);
  transpose_cvt<<<dim3(H / 32, H / 32), 256, 0, stream>>>(Wo, WoT, H, H);
  gemm_bt<__bf16><<<dim3(H3 / 128, (B * S) / 128), 256, 0, stream>>>(
      Xb, WqkvT, QKV, B * S, H3, H);
  rope_scatter<<<(B * S * NH * 64) / 256, 256, 0, stream>>>(QKV, Qr, Kr, Vt);
  flash_attn<<<dim3(S / 128, NH, B), 256, 0, stream>>>(Qr, Kr, Vt, AO);
  gemm_bt<float><<<dim3(H / 128, (B * S) / 128), 256, 0, stream>>>(
      AO, WoT, out, B * S, H, H);
}